// Round 1
// baseline (1345.621 us; speedup 1.0000x reference)
//
#include <hip/hip_runtime.h>

// Problem constants
#define HW   128
#define CC   16      // channels per stream
#define CIN  48      // 3 streams concatenated
#define NCELL 16     // 4 cols x 4 rows
#define WPC  20736   // weights per cell: 48*48*9

// ---------------------------------------------------------------------------
// Weight transpose: W[cell][co][ci][kh][kw] -> wT[cell][ci][kh][kw][co]
// so that for fixed (ci,kh,kw) the 48 co weights are contiguous (wide s_load).
// ---------------------------------------------------------------------------
__global__ void transpose_w_k(const float* __restrict__ W, float* __restrict__ wT) {
    int idx = blockIdx.x * 256 + threadIdx.x;
    if (idx >= NCELL * WPC) return;
    int cell = idx / WPC;
    int rem  = idx - cell * WPC;
    int co   = rem / 432;          // 432 = 48*9
    int r2   = rem - co * 432;     // ci*9 + kh*3 + kw
    wT[cell * WPC + r2 * 48 + co] = W[idx];
}

// ---------------------------------------------------------------------------
// One output stream (16 channels) of one conv cell, for this thread's pixel.
// op == nullptr -> stream is dead (never read downstream): skip compute+store.
// ---------------------------------------------------------------------------
__device__ __forceinline__ void compute_stream(
    const float xs[CIN][18][18],
    const float* __restrict__ wc,   // wT for this cell: [ci][kh][kw][co]
    const float* __restrict__ bc,   // bias[48] for this cell
    float* __restrict__ op,         // output stream [B][16][H][W] or null
    int s, int b, int y0, int x0, int tx, int ty)
{
    if (!op) return;
    float acc[CC];
#pragma unroll
    for (int j = 0; j < CC; ++j) acc[j] = bc[s * CC + j];

    for (int ci = 0; ci < CIN; ++ci) {
#pragma unroll
        for (int kh = 0; kh < 3; ++kh) {
#pragma unroll
            for (int kw = 0; kw < 3; ++kw) {
                float xv = xs[ci][ty + kh][tx + kw];
                const float* wp = wc + (ci * 9 + kh * 3 + kw) * 48 + s * CC;
#pragma unroll
                for (int j = 0; j < CC; ++j)
                    acc[j] = fmaf(xv, wp[j], acc[j]);
            }
        }
    }

    const int y = y0 + ty, xg = x0 + tx;
#pragma unroll
    for (int j = 0; j < CC; ++j) {
        float v = acc[j] > 0.f ? acc[j] : 0.f;  // ReLU
        op[(((size_t)b * CC + j) * HW + y) * HW + xg] = v;
    }
}

// ---------------------------------------------------------------------------
// One grid-cell conv: x_cat = concat(in0,in1,in2) (null slot -> zeros),
// y = relu(conv3x3_same(x_cat, W) + b), streams: right=y[0:16], up=y[16:32],
// down=y[32:48] written to oR/oU/oD (null -> stream dead, skipped).
// Block: 256 threads = 16x16 spatial tile of one batch element.
// ---------------------------------------------------------------------------
__global__ __launch_bounds__(256, 2) void conv_cell_k(
    const float* __restrict__ in0, const float* __restrict__ in1,
    const float* __restrict__ in2,
    const float* __restrict__ wc, const float* __restrict__ bc,
    float* __restrict__ oR, float* __restrict__ oU, float* __restrict__ oD)
{
    __shared__ float xs[CIN][18][18];   // 62208 B

    const int tid = threadIdx.x;
    const int x0 = blockIdx.x * 16, y0 = blockIdx.y * 16, b = blockIdx.z;

    // Stage 48ch x 18x18 halo tile into LDS (zero-pad borders & null slots).
    for (int idx = tid; idx < CIN * 18 * 18; idx += 256) {
        int ci  = idx / 324;
        int rem = idx - ci * 324;
        int iy  = rem / 18;
        int ix  = rem - iy * 18;
        int gy = y0 + iy - 1, gx = x0 + ix - 1;
        const float* p = (ci < 16) ? in0 : (ci < 32 ? in1 : in2);
        float v = 0.f;
        if (p && (unsigned)gy < (unsigned)HW && (unsigned)gx < (unsigned)HW)
            v = p[(((size_t)b * CC + (ci & 15)) * HW + gy) * HW + gx];
        (&xs[0][0][0])[idx] = v;
    }
    __syncthreads();

    const int tx = tid & 15, ty = tid >> 4;
    compute_stream(xs, wc, bc, oR, 0, b, y0, x0, tx, ty);
    compute_stream(xs, wc, bc, oU, 1, b, y0, x0, tx, ty);
    compute_stream(xs, wc, bc, oD, 2, b, y0, x0, tx, ty);
}

// ---------------------------------------------------------------------------
// Orchestration: wavefront sweep col 0..3, row 0..3 (strictly sequential on
// `stream`). Stream buffers in workspace:
//   R[parity][row]  right streams (ping-pong by column parity)   8 x 8MB
//   U[row]          up streams (single set: U[r] consumed by (c,r-1) before
//                   (c,r) overwrites it)                          4 x 8MB
//   D[row&1]        down streams within a column (ping-pong)      2 x 8MB
// Total ws: 16*WPC + 14*S floats = ~113.3 MB.
// ---------------------------------------------------------------------------
extern "C" void kernel_launch(void* const* d_in, const int* in_sizes, int n_in,
                              void* d_out, int out_size, void* d_ws, size_t ws_size,
                              hipStream_t stream) {
    const float* x  = (const float*)d_in[0];   // [8,16,128,128]
    const float* W  = (const float*)d_in[1];   // [4,4,48,48,3,3]
    const float* bi = (const float*)d_in[2];   // [4,4,48]
    float* out = (float*)d_out;                // [8,16,128,128]
    float* ws  = (float*)d_ws;

    const size_t S = (size_t)8 * CC * HW * HW; // 2097152 floats per stream buf

    float* wT = ws;
    float* p  = ws + (size_t)NCELL * WPC;
    float* R[2][4]; float* U[4]; float* D[2];
    for (int pa = 0; pa < 2; ++pa)
        for (int r = 0; r < 4; ++r) { R[pa][r] = p; p += S; }
    for (int r = 0; r < 4; ++r) { U[r] = p; p += S; }
    for (int d = 0; d < 2; ++d) { D[d] = p; p += S; }

    hipLaunchKernelGGL(transpose_w_k, dim3((NCELL * WPC + 255) / 256), dim3(256),
                       0, stream, W, wT);

    dim3 grid(8, 8, 8), blk(256);
    for (int col = 0; col < 4; ++col) {
        const int pa = col & 1, pp = pa ^ 1;
        for (int row = 0; row < 4; ++row) {
            const float *in0 = nullptr, *in1 = nullptr, *in2 = nullptr;
            if (col == 0) {
                in0 = (row == 0) ? x : D[(row - 1) & 1];
            } else {
                in0 = R[pp][row];                        // right from prev col
                if (row == 0)      in1 = U[1];           // up from (c-1, 1)
                else if (row == 3) in1 = D[(row - 1) & 1]; // down goes in slot1!
                else { in1 = U[row + 1]; in2 = D[(row - 1) & 1]; }
            }
            float *oR = nullptr, *oU = nullptr, *oD = nullptr;
            if (col < 3) {
                oR = R[pa][row];
                if (row > 0) oU = U[row];   // up of row 0 is never read
                if (row < 3) oD = D[row & 1]; // down of row 3 is never read
            } else {
                // Last column: only the down-chain feeds forward; (3,3).right
                // is the final output.
                if (row < 3) oD = D[row & 1];
                else         oR = out;
            }
            const float* wc = wT + (size_t)(col * 4 + row) * WPC;
            const float* bc = bi + (size_t)(col * 4 + row) * 48;
            hipLaunchKernelGGL(conv_cell_k, grid, blk, 0, stream,
                               in0, in1, in2, wc, bc, oR, oU, oD);
        }
    }
}

// Round 2
// 625.175 us; speedup vs baseline: 2.1524x; 2.1524x over previous
//
#include <hip/hip_runtime.h>

// Problem constants
#define HW    128
#define CC    16      // channels per stream
#define NCELL 16      // 4 cols x 4 rows

typedef _Float16 half8 __attribute__((ext_vector_type(8)));
typedef float    f32x4 __attribute__((ext_vector_type(4)));

#define XS_HALFS 15616          // 18*18*48 = 15552, padded for swizzle + chunk-4 overread
#define ABUF_PER_CELL 46080     // 5 chunks * 3 kh * 2 splits * 4 quads * 48 co * 8

// 16B-granular XOR swizzle (involution, bijective on 8-blocks of units)
__device__ __forceinline__ int swz(int u) { return u ^ ((u >> 3) & 7); }

// ---------------------------------------------------------------------------
// Weight prep: W[cell][co][ci][kh][kw] fp32 -> A-fragment-ordered fp16 hi/lo.
// Abuf layout: [cell][chunk5][kh3][split2][quad4][co48][j8] halfs, where
// k = chunk*32 + quad*8 + j indexes the per-kh K-run (k = kw*48 + ci, 144
// valid, rest zero-padded so MFMA masks the B-side garbage).
// ---------------------------------------------------------------------------
__global__ void prep_w_k(const float* __restrict__ W, _Float16* __restrict__ Abuf) {
    int idx = blockIdx.x * 256 + threadIdx.x;
    if (idx >= NCELL * ABUF_PER_CELL) return;
    int j = idx & 7;
    int t = idx >> 3;
    int co = t % 48;  t /= 48;
    int quad = t & 3; t >>= 2;
    int s = t & 1;    t >>= 1;
    int kh = t % 3;   t /= 3;
    int chunk = t % 5; t /= 5;
    int cell = t;
    int k = chunk * 32 + quad * 8 + j;
    float v = 0.f;
    if (k < 144) {
        int kw = k / 48, ci = k - kw * 48;
        v = W[((size_t)(cell * 48 + co) * 48 + ci) * 9 + kh * 3 + kw];
    }
    _Float16 h = (_Float16)v;
    if (s == 1) h = (_Float16)(v - (float)h);
    Abuf[idx] = h;
}

// ---------------------------------------------------------------------------
// One grid-cell conv as implicit GEMM on MFMA (fp16x3 split = fp32 accuracy).
// Block: 256 thr = 4 waves; 16x16 output pixels of one batch elem.
// Wave w: rows 4w..4w+3 (4 N-tiles of 16 px), all 3 co-tiles (live only).
// ---------------------------------------------------------------------------
__global__ __launch_bounds__(256, 2) void conv_cell_mfma_k(
    const float* __restrict__ in0, const float* __restrict__ in1,
    const float* __restrict__ in2,
    const _Float16* __restrict__ Acell, const float* __restrict__ bc,
    float* __restrict__ oR, float* __restrict__ oU, float* __restrict__ oD)
{
    __shared__ _Float16 xh[XS_HALFS];
    __shared__ _Float16 xl[XS_HALFS];

    const int tid = threadIdx.x;
    const int x0 = blockIdx.x * 16, y0 = blockIdx.y * 16, b = blockIdx.z;

    // ---- stage 48ch x 18x18 halo tile: fp32 -> (hi,lo) fp16, channel-last,
    //      swizzled at 16B granularity ----
    for (int idx = tid; idx < 48 * 324; idx += 256) {
        int ci = idx / 324;
        int rem = idx - ci * 324;
        int iy = rem / 18, ix = rem - iy * 18;      // ix innermost -> coalesced
        int gy = y0 + iy - 1, gx = x0 + ix - 1;
        const float* p = (ci < 16) ? in0 : (ci < 32 ? in1 : in2);
        float v = 0.f;
        if (p && (unsigned)gy < (unsigned)HW && (unsigned)gx < (unsigned)HW)
            v = p[(((size_t)b * CC + (ci & 15)) * HW + gy) * HW + gx];
        _Float16 h = (_Float16)v;
        _Float16 l = (_Float16)(v - (float)h);
        int a = (iy * 18 + ix) * 48 + ci;           // half index, pixel stride 48
        int as = swz(a >> 3) * 8 + (a & 7);
        xh[as] = h;
        xl[as] = l;
    }
    __syncthreads();

    const int lane = tid & 63, wv = tid >> 6;
    const int n = lane & 15, quad = lane >> 4;
    const int py0 = wv * 4;
    const int live = (oR ? 1 : 0) | (oU ? 2 : 0) | (oD ? 4 : 0);

    // acc[cot][nt]: D tile, co = cot*16 + quad*4 + r, pixel = (y0+py0+nt, x0+n)
    f32x4 acc[3][4];
#pragma unroll
    for (int cot = 0; cot < 3; ++cot) {
#pragma unroll
        for (int r = 0; r < 4; ++r) {
            float bv = bc[cot * 16 + quad * 4 + r];
#pragma unroll
            for (int nt = 0; nt < 4; ++nt) acc[cot][nt][r] = bv;
        }
    }

    // ---- K loop: 5 chunks of 32 (per-kh run = 144 = 4.5 chunks) ----
    for (int chunk = 0; chunk < 5; ++chunk) {
        // B-frags for the 6 input rows this wave touches (shared across kh)
        half8 bh[6], bl[6];
#pragma unroll
        for (int r = 0; r < 6; ++r) {
            int P = (py0 + r) * 18 + n;
            int a = P * 48 + chunk * 32 + quad * 8;  // 16B-aligned
            int u = swz(a >> 3) * 8;
            bh[r] = *(const half8*)(xh + u);
            bl[r] = *(const half8*)(xl + u);
        }
#pragma unroll
        for (int kh = 0; kh < 3; ++kh) {
            const _Float16* Ab = Acell + (size_t)((chunk * 3 + kh) * 2) * 1536;
#pragma unroll
            for (int cot = 0; cot < 3; ++cot) {
                if (!(live & (1 << cot))) continue;
                half8 ah = *(const half8*)(Ab + quad * 384 + (cot * 16 + n) * 8);
                half8 al = *(const half8*)(Ab + 1536 + quad * 384 + (cot * 16 + n) * 8);
#pragma unroll
                for (int nt = 0; nt < 4; ++nt) {
                    half8 B = bh[nt + kh];
                    acc[cot][nt] = __builtin_amdgcn_mfma_f32_16x16x32_f16(ah, B, acc[cot][nt], 0, 0, 0);
                    acc[cot][nt] = __builtin_amdgcn_mfma_f32_16x16x32_f16(ah, bl[nt + kh], acc[cot][nt], 0, 0, 0);
                    acc[cot][nt] = __builtin_amdgcn_mfma_f32_16x16x32_f16(al, B, acc[cot][nt], 0, 0, 0);
                }
            }
        }
    }

    // ---- epilogue: ReLU + store (C layout: col=lane&15=px, row=quad*4+r=co) ----
    float* outs[3] = {oR, oU, oD};
#pragma unroll
    for (int cot = 0; cot < 3; ++cot) {
        float* op = outs[cot];
        if (!op) continue;
#pragma unroll
        for (int nt = 0; nt < 4; ++nt) {
            int y = y0 + py0 + nt, x = x0 + n;
#pragma unroll
            for (int r = 0; r < 4; ++r) {
                int c = quad * 4 + r;
                float v = acc[cot][nt][r];
                op[(((size_t)b * CC + c) * HW + y) * HW + x] = v > 0.f ? v : 0.f;
            }
        }
    }
}

// ---------------------------------------------------------------------------
// Orchestration: wavefront sweep (proven in round 1). Stream bufs (fp32):
//   R[parity][row] 8x8MB, U[1..3] 3x8MB (row-0 up is dead), D[row&1] 2x8MB.
// ws: Abuf 5.9MB + 13 x 8MB = ~115MB.
// ---------------------------------------------------------------------------
extern "C" void kernel_launch(void* const* d_in, const int* in_sizes, int n_in,
                              void* d_out, int out_size, void* d_ws, size_t ws_size,
                              hipStream_t stream) {
    const float* x  = (const float*)d_in[0];   // [8,16,128,128]
    const float* W  = (const float*)d_in[1];   // [4,4,48,48,3,3]
    const float* bi = (const float*)d_in[2];   // [4,4,48]
    float* out = (float*)d_out;                // [8,16,128,128]

    _Float16* Abuf = (_Float16*)d_ws;
    float* p = (float*)((char*)d_ws + (size_t)NCELL * ABUF_PER_CELL * 2);

    const size_t S = (size_t)8 * CC * HW * HW; // floats per stream buffer
    float* R[2][4]; float* U[4]; float* D[2];
    for (int pa = 0; pa < 2; ++pa)
        for (int r = 0; r < 4; ++r) { R[pa][r] = p; p += S; }
    U[0] = nullptr;
    for (int r = 1; r < 4; ++r) { U[r] = p; p += S; }
    for (int d = 0; d < 2; ++d) { D[d] = p; p += S; }

    hipLaunchKernelGGL(prep_w_k, dim3((NCELL * ABUF_PER_CELL + 255) / 256),
                       dim3(256), 0, stream, W, Abuf);

    dim3 grid(8, 8, 8), blk(256);
    for (int col = 0; col < 4; ++col) {
        const int pa = col & 1, pp = pa ^ 1;
        for (int row = 0; row < 4; ++row) {
            const float *in0 = nullptr, *in1 = nullptr, *in2 = nullptr;
            if (col == 0) {
                in0 = (row == 0) ? x : D[(row - 1) & 1];
            } else {
                in0 = R[pp][row];
                if (row == 0)      in1 = U[1];
                else if (row == 3) in1 = D[(row - 1) & 1];
                else { in1 = U[row + 1]; in2 = D[(row - 1) & 1]; }
            }
            float *oR = nullptr, *oU = nullptr, *oD = nullptr;
            if (col < 3) {
                oR = R[pa][row];
                if (row > 0) oU = U[row];
                if (row < 3) oD = D[row & 1];
            } else {
                if (row < 3) oD = D[row & 1];
                else         oR = out;
            }
            const _Float16* Ac = Abuf + (size_t)(col * 4 + row) * ABUF_PER_CELL;
            const float*    bc = bi + (size_t)(col * 4 + row) * 48;
            hipLaunchKernelGGL(conv_cell_mfma_k, grid, blk, 0, stream,
                               in0, in1, in2, Ac, bc, oR, oU, oD);
        }
    }
}

// Round 4
// 405.967 us; speedup vs baseline: 3.3146x; 1.5400x over previous
//
#include <hip/hip_runtime.h>

// Problem constants
#define HW    128
#define NCELL 16
#define ABUF_PER_CELL 46080     // 5 chunks * 3 kh * 2 splits * 4 quads * 48 co * 8

typedef _Float16 half8 __attribute__((ext_vector_type(8)));
typedef float    f32x4 __attribute__((ext_vector_type(4)));

// 16B-granular XOR swizzle (permutes within 8-unit groups; involution)
__device__ __forceinline__ int swz(int u) { return u ^ ((u >> 3) & 7); }

// ---------------------------------------------------------------------------
// Weight prep: W[cell][co][ci][kh][kw] fp32 -> A-fragment-ordered fp16 hi/lo.
// Abuf: [cell][chunk5][kh3][split2][quad4][co48][j8] halfs; k = chunk*32 +
// quad*8 + j indexes the per-kh K-run (k = kw*48 + ci; 144 valid, rest 0).
// (Unchanged from round 2 — validated.)
// ---------------------------------------------------------------------------
__global__ void prep_w_k(const float* __restrict__ W, _Float16* __restrict__ Abuf) {
    int idx = blockIdx.x * 256 + threadIdx.x;
    if (idx >= NCELL * ABUF_PER_CELL) return;
    int j = idx & 7;
    int t = idx >> 3;
    int co = t % 48;  t /= 48;
    int quad = t & 3; t >>= 2;
    int s = t & 1;    t >>= 1;
    int kh = t % 3;   t /= 3;
    int chunk = t % 5; t /= 5;
    int cell = t;
    int k = chunk * 32 + quad * 8 + j;
    float v = 0.f;
    if (k < 144) {
        int kw = k / 48, ci = k - kw * 48;
        v = W[((size_t)(cell * 48 + co) * 48 + ci) * 9 + kh * 3 + kw];
    }
    _Float16 h = (_Float16)v;
    if (s == 1) h = (_Float16)(v - (float)h);
    Abuf[idx] = h;
}

// ---------------------------------------------------------------------------
// One grid-cell conv, implicit GEMM on MFMA (fp16x3 split = fp32 accuracy).
// Streams are fp32 NCHW [b][16][128][128] (round-2 proven format).
// LIVE: compile-time mask of live output streams (1=right,2=up,4=down).
// NIN : compile-time number of live input slots (slots >= NIN are zeros).
// Block: 256 thr = 4 waves, 16x16 px of one batch elem; wave w: rows 4w..4w+3.
// ---------------------------------------------------------------------------
template<int LIVE, int NIN>
__global__ __launch_bounds__(256, 2) void conv_cell_k(
    const float* __restrict__ in0, const float* __restrict__ in1,
    const float* __restrict__ in2,
    const _Float16* __restrict__ Ac, const float* __restrict__ bc,
    float* __restrict__ o0, float* __restrict__ o1, float* __restrict__ o2)
{
    __shared__ __align__(16) _Float16 xh[15616];
    __shared__ __align__(16) _Float16 xl[15616];

    const int tid = threadIdx.x;
    const int x0 = blockIdx.x * 16, y0 = blockIdx.y * 16, b = blockIdx.z;

    // Zero the swizzle-overread tail (units 1944..1951): the chunk-4
    // k in [144,160) B-reads touch these; A is zero there but 0*NaN = NaN.
    if (tid < 64) { xh[15552 + tid] = (_Float16)0.f; xl[15552 + tid] = (_Float16)0.f; }

    // ---- stage 48ch x 18x18 halo: 864 row-tasks (ci, iy); fp32 NCHW ->
    //      h/l split, channel-last (pixel stride 48), 16B-swizzled ----
    for (int task = tid; task < 864; task += 256) {
        int ci = task / 18, iy = task - ci * 18;
        float v[18];
#pragma unroll
        for (int ix = 0; ix < 18; ++ix) v[ix] = 0.f;
        if (ci < NIN * 16) {                              // compile-time prune
            const float* p = (ci < 16) ? in0 : (ci < 32 ? in1 : in2);
            int gy = y0 + iy - 1;
            if ((unsigned)gy < (unsigned)HW) {
                const float* rp = p + (((size_t)b * 16 + (ci & 15)) * HW + gy) * HW + x0;
                f32x4 q0 = *(const f32x4*)(rp);
                f32x4 q1 = *(const f32x4*)(rp + 4);
                f32x4 q2 = *(const f32x4*)(rp + 8);
                f32x4 q3 = *(const f32x4*)(rp + 12);
#pragma unroll
                for (int j = 0; j < 4; ++j) {
                    v[1 + j] = q0[j]; v[5 + j] = q1[j];
                    v[9 + j] = q2[j]; v[13 + j] = q3[j];
                }
                if (x0 > 0)       v[0]  = rp[-1];
                if (x0 < HW - 16) v[17] = rp[16];
            }
        }
#pragma unroll
        for (int ix = 0; ix < 18; ++ix) {
            float fv = v[ix];
            _Float16 h = (_Float16)fv;
            _Float16 l = (_Float16)(fv - (float)h);
            int a = (iy * 18 + ix) * 48 + ci;
            int as = swz(a >> 3) * 8 + (a & 7);
            xh[as] = h; xl[as] = l;
        }
    }
    __syncthreads();

    const int lane = tid & 63, wv = tid >> 6;
    const int n = lane & 15, quad = lane >> 4;
    const int py0 = wv * 4;

    // acc[cot][nt]: D tile, co = cot*16 + quad*4 + r, pixel (y0+py0+nt, x0+n)
    f32x4 acc[3][4];
#pragma unroll
    for (int cot = 0; cot < 3; ++cot) {
        if (!(LIVE & (1 << cot))) continue;
#pragma unroll
        for (int r = 0; r < 4; ++r) {
            float bv = bc[cot * 16 + quad * 4 + r];
#pragma unroll
            for (int nt = 0; nt < 4; ++nt) acc[cot][nt][r] = bv;
        }
    }

    // ---- K loop: 5 chunks of 32 over the per-kh (kw,ci) run, branch-free ----
#pragma unroll
    for (int chunk = 0; chunk < 5; ++chunk) {
        half8 bh[6], bl[6];
#pragma unroll
        for (int r = 0; r < 6; ++r) {
            int a = ((py0 + r) * 18 + n) * 48 + chunk * 32 + quad * 8;
            int u = swz(a >> 3) * 8;
            bh[r] = *(const half8*)(xh + u);
            bl[r] = *(const half8*)(xl + u);
        }
#pragma unroll
        for (int kh = 0; kh < 3; ++kh) {
            const _Float16* Ab = Ac + (size_t)((chunk * 3 + kh) * 2) * 1536;
#pragma unroll
            for (int cot = 0; cot < 3; ++cot) {
                if (!(LIVE & (1 << cot))) continue;   // compile-time
                half8 ah = *(const half8*)(Ab + quad * 384 + (cot * 16 + n) * 8);
                half8 al = *(const half8*)(Ab + 1536 + quad * 384 + (cot * 16 + n) * 8);
#pragma unroll
                for (int nt = 0; nt < 4; ++nt) {
                    acc[cot][nt] = __builtin_amdgcn_mfma_f32_16x16x32_f16(ah, bh[nt + kh], acc[cot][nt], 0, 0, 0);
                    acc[cot][nt] = __builtin_amdgcn_mfma_f32_16x16x32_f16(al, bh[nt + kh], acc[cot][nt], 0, 0, 0);
                    acc[cot][nt] = __builtin_amdgcn_mfma_f32_16x16x32_f16(ah, bl[nt + kh], acc[cot][nt], 0, 0, 0);
                }
            }
        }
    }

    // ---- epilogue: ReLU + direct fp32 NCHW stores (round-2 proven) ----
    float* const outs[3] = {o0, o1, o2};
#pragma unroll
    for (int cot = 0; cot < 3; ++cot) {
        if (!(LIVE & (1 << cot))) continue;
        float* op = outs[cot];
#pragma unroll
        for (int nt = 0; nt < 4; ++nt) {
            int y = y0 + py0 + nt, xg = x0 + n;
#pragma unroll
            for (int r = 0; r < 4; ++r) {
                float vv = acc[cot][nt][r];
                op[(((size_t)b * 16 + quad * 4 + r) * HW + y) * HW + xg] = vv > 0.f ? vv : 0.f;
            }
        }
    }
}

// ---------------------------------------------------------------------------
// Orchestration: wavefront sweep col 0..3, row 0..3, sequential on `stream`.
// fp32 stream buffers (round-2 proven): R[parity][row] 8x8MB, U[1..3] 3x8MB
// (row-0 up dead), D[row&1] 2x8MB. ws: Abuf 1.47MB + 13 x 8.39MB = ~110.5MB.
// ---------------------------------------------------------------------------
extern "C" void kernel_launch(void* const* d_in, const int* in_sizes, int n_in,
                              void* d_out, int out_size, void* d_ws, size_t ws_size,
                              hipStream_t stream) {
    const float* x  = (const float*)d_in[0];   // [8,16,128,128]
    const float* W  = (const float*)d_in[1];   // [4,4,48,48,3,3]
    const float* bi = (const float*)d_in[2];   // [4,4,48]
    float* out = (float*)d_out;                // [8,16,128,128]

    _Float16* Abuf = (_Float16*)d_ws;
    float* p = (float*)((char*)d_ws + (size_t)NCELL * ABUF_PER_CELL * 2);
    const size_t S = (size_t)8 * 16 * HW * HW; // floats per stream buffer

    float* R[2][4]; float* U[4]; float* D[2];
    for (int pa = 0; pa < 2; ++pa)
        for (int r = 0; r < 4; ++r) { R[pa][r] = p; p += S; }
    U[0] = nullptr;
    for (int r = 1; r < 4; ++r) { U[r] = p; p += S; }
    for (int d2 = 0; d2 < 2; ++d2) { D[d2] = p; p += S; }

    hipLaunchKernelGGL(prep_w_k, dim3((NCELL * ABUF_PER_CELL + 255) / 256),
                       dim3(256), 0, stream, W, Abuf);

    dim3 grid(8, 8, 8), blk(256);
    for (int col = 0; col < 4; ++col) {
        const int pa = col & 1, pp = pa ^ 1;
        for (int row = 0; row < 4; ++row) {
            const float *in0 = nullptr, *in1 = nullptr, *in2 = nullptr;
            int nin;
            if (col == 0) {
                in0 = (row == 0) ? x : D[(row - 1) & 1];
                nin = 1;
            } else {
                in0 = R[pp][row];
                if (row == 0)      { in1 = U[1]; nin = 2; }
                else if (row == 3) { in1 = D[(row - 1) & 1]; nin = 2; }
                else { in1 = U[row + 1]; in2 = D[(row - 1) & 1]; nin = 3; }
            }
            float *o0 = nullptr, *o1 = nullptr, *o2 = nullptr;
            int live = 0;
            if (col < 3) {
                o0 = R[pa][row]; live |= 1;
                if (row > 0) { o1 = U[row]; live |= 2; }
                if (row < 3) { o2 = D[row & 1]; live |= 4; }
            } else {
                if (row < 3) { o2 = D[row & 1]; live |= 4; }
                else         { o0 = out; live |= 1; }
            }
            const _Float16* Acell = Abuf + (size_t)(col * 4 + row) * ABUF_PER_CELL;
            const float*    bcell = bi + (size_t)(col * 4 + row) * 48;
#define LNCH(LV, NI) hipLaunchKernelGGL((conv_cell_k<LV, NI>), grid, blk, 0, stream, \
            in0, in1, in2, Acell, bcell, o0, o1, o2)
            switch (live | (nin << 4)) {
                case 21: LNCH(5, 1); break;   // col0 row0
                case 23: LNCH(7, 1); break;   // col0 rows1-2
                case 19: LNCH(3, 1); break;   // col0 row3
                case 37: LNCH(5, 2); break;   // col1-2 row0
                case 55: LNCH(7, 3); break;   // col1-2 rows1-2
                case 35: LNCH(3, 2); break;   // col1-2 row3
                case 36: LNCH(4, 2); break;   // col3 row0
                case 52: LNCH(4, 3); break;   // col3 rows1-2
                case 33: LNCH(1, 2); break;   // col3 row3 (final -> d_out)
            }
#undef LNCH
        }
    }
}

// Round 5
// 383.822 us; speedup vs baseline: 3.5058x; 1.0577x over previous
//
#include <hip/hip_runtime.h>

// Problem constants
#define HW    128
#define NCELL 16
#define ABUF_PER_CELL 46080     // 5 chunks * 3 kh * 2 splits * 4 quads * 48 co * 8

typedef _Float16 half8 __attribute__((ext_vector_type(8)));
typedef float    f32x4 __attribute__((ext_vector_type(4)));

// 16B-granular XOR swizzle (permutes within 8-unit groups; involution)
__device__ __forceinline__ int swz(int u) { return u ^ ((u >> 3) & 7); }

// ---------------------------------------------------------------------------
// Weight prep: W[cell][co][ci][kh][kw] fp32 -> A-fragment-ordered fp16 hi/lo.
// Abuf: [cell][chunk5][kh3][split2][quad4][co48][j8] halfs; k = chunk*32 +
// quad*8 + j indexes the per-kh K-run (k = kw*48 + ci; 144 valid, rest 0).
// (Validated rounds 2-4.)
// ---------------------------------------------------------------------------
__global__ void prep_w_k(const float* __restrict__ W, _Float16* __restrict__ Abuf) {
    int idx = blockIdx.x * 256 + threadIdx.x;
    if (idx >= NCELL * ABUF_PER_CELL) return;
    int j = idx & 7;
    int t = idx >> 3;
    int co = t % 48;  t /= 48;
    int quad = t & 3; t >>= 2;
    int s = t & 1;    t >>= 1;
    int kh = t % 3;   t /= 3;
    int chunk = t % 5; t /= 5;
    int cell = t;
    int k = chunk * 32 + quad * 8 + j;
    float v = 0.f;
    if (k < 144) {
        int kw = k / 48, ci = k - kw * 48;
        v = W[((size_t)(cell * 48 + co) * 48 + ci) * 9 + kh * 3 + kw];
    }
    _Float16 h = (_Float16)v;
    if (s == 1) h = (_Float16)(v - (float)h);
    Abuf[idx] = h;
}

// Per-cell I/O descriptor (fp32 NCHW streams, round-4 proven format)
struct CellIO {
    const float* in0; const float* in1; const float* in2;
    const _Float16* Ac; const float* bc;
    float* o0; float* o1; float* o2;
};

// ---------------------------------------------------------------------------
// One grid-cell conv body, implicit GEMM on MFMA (fp16x3 = fp32 accuracy).
// LIVE: compile-time mask of live output streams (1=right,2=up,4=down).
// NIN : compile-time number of live input slots.
// K-loop: flat 15 iterations (chunk,kh), explicit double-buffered register
// prefetch of A (global, one it ahead) and B (LDS, one chunk ahead).
// ---------------------------------------------------------------------------
template<int LIVE, int NIN>
__device__ __forceinline__ void cell_body(const CellIO& P, int b,
                                          _Float16* xh, _Float16* xl)
{
    const int tid = threadIdx.x;
    const int x0 = blockIdx.x * 16, y0 = blockIdx.y * 16;

    // Zero the swizzle-overread tail (units 1944..1951): chunk-4 k in
    // [144,160) B-reads touch these; A is zero there but 0*NaN = NaN.
    if (tid < 64) { xh[15552 + tid] = (_Float16)0.f; xl[15552 + tid] = (_Float16)0.f; }

    // ---- stage 48ch x 18x18 halo: 864 row-tasks (ci, iy); fp32 NCHW ->
    //      h/l split, channel-last (pixel stride 48), 16B-swizzled ----
    for (int task = tid; task < 864; task += 256) {
        int ci = task / 18, iy = task - ci * 18;
        float v[18];
#pragma unroll
        for (int ix = 0; ix < 18; ++ix) v[ix] = 0.f;
        if (ci < NIN * 16) {                              // compile-time prune
            const float* p = (ci < 16) ? P.in0 : (ci < 32 ? P.in1 : P.in2);
            int gy = y0 + iy - 1;
            if ((unsigned)gy < (unsigned)HW) {
                const float* rp = p + (((size_t)b * 16 + (ci & 15)) * HW + gy) * HW + x0;
                f32x4 q0 = *(const f32x4*)(rp);
                f32x4 q1 = *(const f32x4*)(rp + 4);
                f32x4 q2 = *(const f32x4*)(rp + 8);
                f32x4 q3 = *(const f32x4*)(rp + 12);
#pragma unroll
                for (int j = 0; j < 4; ++j) {
                    v[1 + j] = q0[j]; v[5 + j] = q1[j];
                    v[9 + j] = q2[j]; v[13 + j] = q3[j];
                }
                if (x0 > 0)       v[0]  = rp[-1];
                if (x0 < HW - 16) v[17] = rp[16];
            }
        }
#pragma unroll
        for (int ix = 0; ix < 18; ++ix) {
            float fv = v[ix];
            _Float16 h = (_Float16)fv;
            _Float16 l = (_Float16)(fv - (float)h);
            int a = (iy * 18 + ix) * 48 + ci;
            int as = swz(a >> 3) * 8 + (a & 7);
            xh[as] = h; xl[as] = l;
        }
    }
    __syncthreads();

    const int lane = tid & 63, wv = tid >> 6;
    const int n = lane & 15, quad = lane >> 4;
    const int py0 = wv * 4;

    // acc[cot][nt]: D tile, co = cot*16 + quad*4 + r, pixel (y0+py0+nt, x0+n)
    f32x4 acc[3][4];
#pragma unroll
    for (int cot = 0; cot < 3; ++cot) {
        if (!(LIVE & (1 << cot))) continue;
#pragma unroll
        for (int r = 0; r < 4; ++r) {
            float bv = P.bc[cot * 16 + quad * 4 + r];
#pragma unroll
            for (int nt = 0; nt < 4; ++nt) acc[cot][nt][r] = bv;
        }
    }

    // ---- K loop: 15 its (chunk,kh), double-buffered A (global) + B (LDS) ----
    const _Float16* Abase = P.Ac + quad * 384 + n * 8;
    half8 Ah[2][3], Al[2][3];
    half8 Bh[2][6], Bl[2][6];

    auto loadA = [&](int it, int buf) {
        const _Float16* Ab = Abase + (size_t)(it * 2) * 1536;
#pragma unroll
        for (int cot = 0; cot < 3; ++cot) {
            if (!(LIVE & (1 << cot))) continue;
            Ah[buf][cot] = *(const half8*)(Ab + cot * 128);
            Al[buf][cot] = *(const half8*)(Ab + 1536 + cot * 128);
        }
    };
    auto loadB = [&](int chunk, int buf) {
#pragma unroll
        for (int r = 0; r < 6; ++r) {
            int a = ((py0 + r) * 18 + n) * 48 + chunk * 32 + quad * 8;
            int u = swz(a >> 3) * 8;
            Bh[buf][r] = *(const half8*)(xh + u);
            Bl[buf][r] = *(const half8*)(xl + u);
        }
    };

    loadA(0, 0);
    loadB(0, 0);
#pragma unroll
    for (int it = 0; it < 15; ++it) {
        const int chunk = it / 3, kh = it - chunk * 3;
        const int ab = it & 1, bb = chunk & 1;
        if (it < 14) loadA(it + 1, ab ^ 1);              // prefetch next A
        if (kh == 0 && chunk < 4) loadB(chunk + 1, bb ^ 1); // prefetch next B
#pragma unroll
        for (int cot = 0; cot < 3; ++cot) {
            if (!(LIVE & (1 << cot))) continue;
#pragma unroll
            for (int nt = 0; nt < 4; ++nt) {
                acc[cot][nt] = __builtin_amdgcn_mfma_f32_16x16x32_f16(Ah[ab][cot], Bh[bb][nt + kh], acc[cot][nt], 0, 0, 0);
                acc[cot][nt] = __builtin_amdgcn_mfma_f32_16x16x32_f16(Al[ab][cot], Bh[bb][nt + kh], acc[cot][nt], 0, 0, 0);
                acc[cot][nt] = __builtin_amdgcn_mfma_f32_16x16x32_f16(Ah[ab][cot], Bl[bb][nt + kh], acc[cot][nt], 0, 0, 0);
            }
        }
    }

    // ---- epilogue: ReLU + direct fp32 NCHW stores (round-4 proven) ----
    float* const outs[3] = {P.o0, P.o1, P.o2};
#pragma unroll
    for (int cot = 0; cot < 3; ++cot) {
        if (!(LIVE & (1 << cot))) continue;
        float* op = outs[cot];
#pragma unroll
        for (int nt = 0; nt < 4; ++nt) {
            int y = y0 + py0 + nt, xg = x0 + n;
#pragma unroll
            for (int r = 0; r < 4; ++r) {
                float vv = acc[cot][nt][r];
                op[(((size_t)b * 16 + quad * 4 + r) * HW + y) * HW + xg] = vv > 0.f ? vv : 0.f;
            }
        }
    }
}

// ---------------------------------------------------------------------------
// Stage kernel: one or two independent cells per launch. blockIdx.z < 8 ->
// cell 0 (batch z), z >= 8 -> cell 1 (batch z-8). L1==0 -> single-cell.
// ---------------------------------------------------------------------------
template<int L0, int N0, int L1, int N1>
__global__ __launch_bounds__(256, 2) void cell_k(CellIO P0, CellIO P1) {
    __shared__ __align__(16) _Float16 xh[15616];
    __shared__ __align__(16) _Float16 xl[15616];
    int b = blockIdx.z & 7;
    if constexpr (L1 > 0) {
        if (blockIdx.z >= 8) { cell_body<L1, N1>(P1, b, xh, xl); return; }
    }
    cell_body<L0, N0>(P0, b, xh, xl);
}

// ---------------------------------------------------------------------------
// Orchestration: anti-diagonal stage schedule s = 2*col + row; cells within a
// stage are independent (deps land at s-1 / s-2; verified per-buffer).
// Buffers: R[colpar][row] x8, U[1..3] x3, D[colpar][rowpar] x4 (pair mode) or
// D aliased to 2 (sequential fallback if ws too small = round-4 scheme).
// ---------------------------------------------------------------------------
extern "C" void kernel_launch(void* const* d_in, const int* in_sizes, int n_in,
                              void* d_out, int out_size, void* d_ws, size_t ws_size,
                              hipStream_t stream) {
    const float* x  = (const float*)d_in[0];   // [8,16,128,128]
    const float* W  = (const float*)d_in[1];   // [4,4,48,48,3,3]
    const float* bi = (const float*)d_in[2];   // [4,4,48]
    float* out = (float*)d_out;                // [8,16,128,128]

    _Float16* Abuf = (_Float16*)d_ws;
    const size_t abytes = (size_t)NCELL * ABUF_PER_CELL * 2;   // 1.47 MB
    float* q = (float*)((char*)d_ws + abytes);
    const size_t S = (size_t)8 * 16 * HW * HW;                 // floats/buffer

    const bool pair_ok = ws_size >= abytes + (size_t)15 * S * 4;

    float *R[2][4], *U[4], *D[2][2];
    for (int pa = 0; pa < 2; ++pa)
        for (int r = 0; r < 4; ++r) { R[pa][r] = q; q += S; }
    U[0] = nullptr;
    for (int r = 1; r < 4; ++r) { U[r] = q; q += S; }
    D[0][0] = q; q += S; D[0][1] = q; q += S;
    if (pair_ok) { D[1][0] = q; q += S; D[1][1] = q; q += S; }
    else         { D[1][0] = D[0][0];   D[1][1] = D[0][1]; }   // round-4 alias

    hipLaunchKernelGGL(prep_w_k, dim3((NCELL * ABUF_PER_CELL + 255) / 256),
                       dim3(256), 0, stream, W, Abuf);

    auto mkio = [&](int c, int r) -> CellIO {
        CellIO io{};
        if (c == 0) {
            io.in0 = (r == 0) ? x : D[0][(r - 1) & 1];
        } else {
            io.in0 = R[(c - 1) & 1][r];
            if (r == 0)      io.in1 = U[1];
            else if (r == 3) io.in1 = D[c & 1][0];
            else { io.in1 = U[r + 1]; io.in2 = D[c & 1][(r - 1) & 1]; }
        }
        if (c < 3) {
            io.o0 = R[c & 1][r];
            if (r > 0) io.o1 = U[r];
            if (r < 3) io.o2 = D[c & 1][r & 1];
        } else {
            if (r < 3) io.o2 = D[1][r & 1];
            else       io.o0 = out;
        }
        io.Ac = Abuf + (size_t)(c * 4 + r) * ABUF_PER_CELL;
        io.bc = bi + (size_t)(c * 4 + r) * 48;
        return io;
    };

    dim3 blk(256), g1(8, 8, 8), g2(8, 8, 16);
#define ONE(L, N, c, r)  do { CellIO a = mkio(c, r); \
    hipLaunchKernelGGL((cell_k<L, N, 0, 0>), g1, blk, 0, stream, a, a); } while (0)
#define TWO(L0, N0, c0, r0, L1, N1, c1, r1) do { \
    CellIO a = mkio(c0, r0), bb2 = mkio(c1, r1); \
    hipLaunchKernelGGL((cell_k<L0, N0, L1, N1>), g2, blk, 0, stream, a, bb2); } while (0)
#define ONEP(L0, N0, c, r, L1, N1) do { CellIO a = mkio(c, r); \
    hipLaunchKernelGGL((cell_k<L0, N0, L1, N1>), g1, blk, 0, stream, a, a); } while (0)

    if (pair_ok) {
        ONE(5, 1, 0, 0);
        ONE(7, 1, 0, 1);
        TWO(7, 1, 0, 2,  5, 2, 1, 0);
        TWO(3, 1, 0, 3,  7, 3, 1, 1);
        TWO(7, 3, 1, 2,  5, 2, 2, 0);
        TWO(3, 2, 1, 3,  7, 3, 2, 1);
        TWO(7, 3, 2, 2,  4, 2, 3, 0);
        TWO(3, 2, 2, 3,  4, 3, 3, 1);
        ONE(4, 3, 3, 2);
        ONE(1, 2, 3, 3);
    } else {
        // Sequential col-major fallback (round-4 proven order); reuse pair
        // kernels with z=8 so only P0 executes.
        ONE(5, 1, 0, 0);
        ONE(7, 1, 0, 1);
        ONEP(7, 1, 0, 2, 5, 2);
        ONEP(3, 1, 0, 3, 7, 3);
        ONEP(5, 2, 1, 0, 0, 0);
        ONEP(7, 3, 1, 1, 0, 0);
        ONEP(7, 3, 1, 2, 0, 0);
        ONEP(3, 2, 1, 3, 7, 3);
        ONEP(5, 2, 2, 0, 0, 0);
        ONEP(7, 3, 2, 1, 0, 0);
        ONEP(7, 3, 2, 2, 4, 2);
        ONEP(3, 2, 2, 3, 4, 3);
        ONEP(4, 2, 3, 0, 0, 0);
        ONEP(4, 3, 3, 1, 0, 0);
        ONE(4, 3, 3, 2);
        ONE(1, 2, 3, 3);
    }
#undef ONE
#undef TWO
#undef ONEP
}